// Round 1
// baseline (1159.600 us; speedup 1.0000x reference)
//
#include <hip/hip_runtime.h>

#define KK 3
#define CIN 256
#define COUT 64
#define NSPLIT 4
#define BB 8
#define HH 64
#define WW 64
#define K2 9
#define OC 18          // 2*K*K offset channels
#define EPS 1e-5f

// ---- workspace layout (in floats) ----
#define WS_SCALE 0
#define WS_BIAS  256
#define WS_BSUM  512
#define WS_HT    1024
#define HT_SIZE  (BB*HH*WW*CIN)            // 8,388,608
#define WS_OFFS  (WS_HT + HT_SIZE)
#define OFFS_SIZE (BB*NSPLIT*OC*HH*WW)     // 2,359,296
#define WS_WDT   (WS_OFFS + OFFS_SIZE)
#define WDT_SIZE (NSPLIT*K2*COUT*COUT)     // 147,456
#define WS_WOT   (WS_WDT + WDT_SIZE)
#define WOT_SIZE (NSPLIT*CIN*OC*K2)        // 663,552

// K0: per-channel BN scale/bias + summed dconv bias
__global__ void prep_kernel(const float* __restrict__ g, const float* __restrict__ be,
                            const float* __restrict__ mn, const float* __restrict__ vr,
                            const float* __restrict__ db, float* __restrict__ ws) {
    int t = threadIdx.x;
    if (t < CIN) {
        float inv = 1.0f / sqrtf(vr[t] + EPS);
        float sc = g[t] * inv;
        ws[WS_SCALE + t] = sc;
        ws[WS_BIAS + t]  = be[t] - mn[t] * sc;
    }
    if (t < COUT) {
        float s = 0.f;
        for (int i = 0; i < NSPLIT; i++) s += db[i * COUT + t];
        ws[WS_BSUM + t] = s;
    }
}

// K0b: weight transposes for scalar-broadcast-friendly layouts
// wdT[((s*9+k)*64+cin)*64+o] = dconv_w[((s*64+o)*64+cin)*9+k]
// woT[((s*256+cin)*18+c)*9+k] = offset_w[((s*18+c)*256+cin)*9+k]
__global__ void wtrans_kernel(const float* __restrict__ dw, const float* __restrict__ ow,
                              float* __restrict__ ws) {
    int tid = blockIdx.x * blockDim.x + threadIdx.x;
    if (tid < WDT_SIZE) {
        int o = tid & 63;
        int c = (tid >> 6) & 63;
        int k = (tid / 4096) % 9;
        int s = tid / 36864;
        ws[WS_WDT + tid] = dw[((s * COUT + o) * COUT + c) * 9 + k];
    }
    if (tid < WOT_SIZE) {
        int k = tid % 9;
        int c = (tid / 9) % OC;
        int cin = (tid / (9 * OC)) % CIN;
        int s = tid / (9 * OC * CIN);
        ws[WS_WOT + tid] = ow[((s * OC + c) * CIN + cin) * 9 + k];
    }
}

// K1: BN+ReLU and NCHW->NHWC transpose of h (for deform sampling)
__global__ __launch_bounds__(256) void bn_transpose_kernel(const float* __restrict__ x,
                                                           float* __restrict__ ws) {
    __shared__ float tile[64 * 65];
    int cg = blockIdx.x;          // channel group of 64
    int y  = blockIdx.y;
    int b  = blockIdx.z;
    int lane = threadIdx.x & 63;
    int grp  = threadIdx.x >> 6;
    #pragma unroll
    for (int i = 0; i < 16; i++) {
        int cl = grp * 16 + i;
        int c  = cg * 64 + cl;
        float v = x[((b * CIN + c) * HH + y) * WW + lane];
        float h = fmaxf(fmaf(v, ws[WS_SCALE + c], ws[WS_BIAS + c]), 0.f);
        tile[cl * 65 + lane] = h;
    }
    __syncthreads();
    #pragma unroll
    for (int i = 0; i < 16; i++) {
        int xx = grp * 16 + i;
        ws[WS_HT + ((b * HH + y) * WW + xx) * CIN + cg * 64 + lane] = tile[lane * 65 + xx];
    }
}

// K2: offset conv (256->18, 3x3, pad 1) with inline BN+ReLU on NCHW x
__global__ __launch_bounds__(256) void offconv_kernel(const float* __restrict__ x,
                                                      const float* __restrict__ offb,
                                                      float* __restrict__ ws) {
    int yblk = blockIdx.x;   // 16
    int s    = blockIdx.y;   // 4
    int b    = blockIdx.z;   // 8
    int lane = threadIdx.x & 63;
    int row  = threadIdx.x >> 6;
    int y = yblk * 4 + row;
    int xx = lane;

    float acc[OC];
    #pragma unroll
    for (int c = 0; c < OC; c++) acc[c] = 0.f;

    const float* woT = ws + WS_WOT + (size_t)s * CIN * OC * 9;

    for (int cin = 0; cin < CIN; cin++) {
        float sc = ws[WS_SCALE + cin];
        float bi = ws[WS_BIAS + cin];
        float tap[9];
        #pragma unroll
        for (int k = 0; k < 9; k++) {
            int dy = k / 3 - 1, dx = k % 3 - 1;
            int yy = y + dy, x2 = xx + dx;
            bool in = (yy >= 0) && (yy < HH) && (x2 >= 0) && (x2 < WW);
            float v = in ? x[((b * CIN + cin) * HH + yy) * WW + x2] : 0.f;
            tap[k] = in ? fmaxf(fmaf(v, sc, bi), 0.f) : 0.f;
        }
        const float* wp = woT + cin * OC * 9;
        #pragma unroll
        for (int c = 0; c < OC; c++) {
            #pragma unroll
            for (int k = 0; k < 9; k++) {
                acc[c] = fmaf(tap[k], wp[c * 9 + k], acc[c]);
            }
        }
    }
    #pragma unroll
    for (int c = 0; c < OC; c++) {
        ws[WS_OFFS + (((b * NSPLIT + s) * OC + c) * HH + y) * WW + xx] = acc[c] + offb[s * OC + c];
    }
}

// K3: deformable conv, all 4 splits accumulated, bias included
__global__ __launch_bounds__(256) void deform_kernel(const float* __restrict__ ws,
                                                     float* __restrict__ out) {
    __shared__ float vbuf[64 * 64];   // [cin][pixel]
    int y = blockIdx.x;
    int b = blockIdx.y;
    int p = threadIdx.x & 63;                                   // pixel x
    int og = __builtin_amdgcn_readfirstlane(threadIdx.x >> 6);  // o-group / cin-group (wave-uniform)

    float acc[16];
    #pragma unroll
    for (int j = 0; j < 16; j++) acc[j] = ws[WS_BSUM + og * 16 + j];

    const float* ht = ws + WS_HT + (size_t)b * HH * WW * CIN;

    for (int s = 0; s < NSPLIT; s++) {
        const float* htc = ht + s * COUT;   // channel offset within NHWC
        for (int k = 0; k < K2; k++) {
            int dy = k / 3 - 1, dx = k % 3 - 1;
            float offy = ws[WS_OFFS + (((b * NSPLIT + s) * OC + 2 * k) * HH + y) * WW + p];
            float offx = ws[WS_OFFS + (((b * NSPLIT + s) * OC + 2 * k + 1) * HH + y) * WW + p];
            float py = (float)(y + dy) + offy;
            float px = (float)(p + dx) + offx;
            float y0f = floorf(py), x0f = floorf(px);
            float wy1 = py - y0f, wx1 = px - x0f;
            float wy0 = 1.f - wy1, wx0 = 1.f - wx1;
            int y0 = (int)y0f, x0 = (int)x0f;

            float v[16];
            #pragma unroll
            for (int j = 0; j < 16; j++) v[j] = 0.f;

            #pragma unroll
            for (int t = 0; t < 4; t++) {
                int yt = y0 + (t >> 1);
                int xt = x0 + (t & 1);
                float wt = ((t >> 1) ? wy1 : wy0) * ((t & 1) ? wx1 : wx0);
                bool valid = (yt >= 0) && (yt < HH) && (xt >= 0) && (xt < WW);
                wt = valid ? wt : 0.f;
                int yi = min(max(yt, 0), HH - 1);
                int xi = min(max(xt, 0), WW - 1);
                const float* srcp = htc + ((size_t)yi * WW + xi) * CIN + og * 16;
                #pragma unroll
                for (int q = 0; q < 4; q++) {
                    float4 f = *(const float4*)(srcp + q * 4);
                    v[q * 4 + 0] = fmaf(wt, f.x, v[q * 4 + 0]);
                    v[q * 4 + 1] = fmaf(wt, f.y, v[q * 4 + 1]);
                    v[q * 4 + 2] = fmaf(wt, f.z, v[q * 4 + 2]);
                    v[q * 4 + 3] = fmaf(wt, f.w, v[q * 4 + 3]);
                }
            }
            #pragma unroll
            for (int j = 0; j < 16; j++) vbuf[(og * 16 + j) * 64 + p] = v[j];
            __syncthreads();

            const float* wp = ws + WS_WDT + (size_t)((s * 9 + k) * 64) * 64;
            #pragma unroll 8
            for (int cin = 0; cin < COUT; cin++) {
                float vv = vbuf[cin * 64 + p];
                #pragma unroll
                for (int j = 0; j < 16; j++) {
                    acc[j] = fmaf(vv, wp[cin * 64 + og * 16 + j], acc[j]);
                }
            }
            __syncthreads();
        }
    }
    #pragma unroll
    for (int j = 0; j < 16; j++) {
        int o = og * 16 + j;
        out[((b * COUT + o) * HH + y) * WW + p] = acc[j];
    }
}

extern "C" void kernel_launch(void* const* d_in, const int* in_sizes, int n_in,
                              void* d_out, int out_size, void* d_ws, size_t ws_size,
                              hipStream_t stream) {
    const float* x        = (const float*)d_in[0];
    const float* bn_gamma = (const float*)d_in[1];
    const float* bn_beta  = (const float*)d_in[2];
    const float* bn_mean  = (const float*)d_in[3];
    const float* bn_var   = (const float*)d_in[4];
    const float* offset_w = (const float*)d_in[5];
    const float* offset_b = (const float*)d_in[6];
    const float* dconv_w  = (const float*)d_in[7];
    const float* dconv_b  = (const float*)d_in[8];
    float* out = (float*)d_out;
    float* ws  = (float*)d_ws;

    prep_kernel<<<1, 256, 0, stream>>>(bn_gamma, bn_beta, bn_mean, bn_var, dconv_b, ws);
    wtrans_kernel<<<(WOT_SIZE + 255) / 256, 256, 0, stream>>>(dconv_w, offset_w, ws);
    bn_transpose_kernel<<<dim3(4, 64, 8), 256, 0, stream>>>(x, ws);
    offconv_kernel<<<dim3(16, 4, 8), 256, 0, stream>>>(x, offset_b, ws);
    deform_kernel<<<dim3(64, 8), 256, 0, stream>>>(ws, out);
}

// Round 2
// 650.622 us; speedup vs baseline: 1.7823x; 1.7823x over previous
//
#include <hip/hip_runtime.h>

#define KK 3
#define CIN 256
#define COUT 64
#define NSPLIT 4
#define BB 8
#define HH 64
#define WW 64
#define K2 9
#define OC 18          // 2*K*K offset channels
#define EPS 1e-5f

// ---- workspace layout (in floats) ----
#define WS_SCALE 0
#define WS_BIAS  256
#define WS_BSUM  512
#define WS_HT    1024
#define HT_SIZE  (BB*HH*WW*CIN)            // 8,388,608
#define WS_OFFS  (WS_HT + HT_SIZE)
#define OFFS_SIZE (BB*NSPLIT*OC*HH*WW)     // 2,359,296
#define WS_WDT   (WS_OFFS + OFFS_SIZE)
#define WDT_SIZE (NSPLIT*K2*COUT*COUT)     // 147,456
#define WS_WOT   (WS_WDT + WDT_SIZE)
#define WOT_SIZE (NSPLIT*CIN*K2*OC)        // 663,552

// K0: per-channel BN scale/bias + summed dconv bias
__global__ void prep_kernel(const float* __restrict__ g, const float* __restrict__ be,
                            const float* __restrict__ mn, const float* __restrict__ vr,
                            const float* __restrict__ db, float* __restrict__ ws) {
    int t = threadIdx.x;
    if (t < CIN) {
        float inv = 1.0f / sqrtf(vr[t] + EPS);
        float sc = g[t] * inv;
        ws[WS_SCALE + t] = sc;
        ws[WS_BIAS + t]  = be[t] - mn[t] * sc;
    }
    if (t < COUT) {
        float s = 0.f;
        for (int i = 0; i < NSPLIT; i++) s += db[i * COUT + t];
        ws[WS_BSUM + t] = s;
    }
}

// K0b: weight transposes
// wdT[((s*9+k)*64+cin)*64+o] = dconv_w[((s*64+o)*64+cin)*9+k]
// woT2[((s*256+cin)*9+k)*18+c] = offset_w[((s*18+c)*256+cin)*9+k]
__global__ void wtrans_kernel(const float* __restrict__ dw, const float* __restrict__ ow,
                              float* __restrict__ ws) {
    int tid = blockIdx.x * blockDim.x + threadIdx.x;
    if (tid < WDT_SIZE) {
        int o = tid & 63;
        int c = (tid >> 6) & 63;
        int k = (tid / 4096) % 9;
        int s = tid / 36864;
        ws[WS_WDT + tid] = dw[((s * COUT + o) * COUT + c) * 9 + k];
    }
    if (tid < WOT_SIZE) {
        int c = tid % OC;
        int k = (tid / OC) % 9;
        int cin = (tid / (9 * OC)) % CIN;
        int s = tid / (9 * OC * CIN);
        ws[WS_WOT + tid] = ow[((s * OC + c) * CIN + cin) * 9 + k];
    }
}

// K1: BN+ReLU and NCHW->NHWC transpose of h (for deform sampling)
__global__ __launch_bounds__(256) void bn_transpose_kernel(const float* __restrict__ x,
                                                           float* __restrict__ ws) {
    __shared__ float tile[64 * 65];
    int cg = blockIdx.x;          // channel group of 64
    int y  = blockIdx.y;
    int b  = blockIdx.z;
    int lane = threadIdx.x & 63;
    int grp  = threadIdx.x >> 6;
    #pragma unroll
    for (int i = 0; i < 16; i++) {
        int cl = grp * 16 + i;
        int c  = cg * 64 + cl;
        float v = x[((b * CIN + c) * HH + y) * WW + lane];
        float h = fmaxf(fmaf(v, ws[WS_SCALE + c], ws[WS_BIAS + c]), 0.f);
        tile[cl * 65 + lane] = h;
    }
    __syncthreads();
    #pragma unroll
    for (int i = 0; i < 16; i++) {
        int xx = grp * 16 + i;
        ws[WS_HT + ((b * HH + y) * WW + xx) * CIN + cg * 64 + lane] = tile[lane * 65 + xx];
    }
}

// K2: offset conv (256->18, 3x3, pad 1), weights staged through LDS
__global__ __launch_bounds__(256) void offconv_kernel(const float* __restrict__ x,
                                                      const float* __restrict__ offb,
                                                      const float* __restrict__ scb,   // ws+WS_SCALE
                                                      const float* __restrict__ woT2,  // ws+WS_WOT
                                                      float* __restrict__ offs_out) {  // ws+WS_OFFS
    // LDS: 32 cin x 9 k x 18 c (padded to 20) = 23040 B
    __shared__ float wlds[32 * 9 * 20];
    int yblk = blockIdx.x;   // 16
    int s    = blockIdx.y;   // 4
    int b    = blockIdx.z;   // 8
    int lane = threadIdx.x & 63;
    int row  = threadIdx.x >> 6;
    int y = yblk * 4 + row;
    int xx = lane;

    float acc[OC];
    #pragma unroll
    for (int c = 0; c < OC; c++) acc[c] = 0.f;

    const float* xb = x + (size_t)b * CIN * HH * WW;

    for (int c8 = 0; c8 < 8; c8++) {
        __syncthreads();   // previous chunk's reads complete
        const float* src = woT2 + ((size_t)(s * CIN + c8 * 32)) * (9 * OC);
        for (int i = threadIdx.x; i < 32 * 9 * OC; i += 256) {
            int cl = i / (9 * OC);
            int r  = i % (9 * OC);
            int k  = r / OC;
            int c  = r % OC;
            wlds[cl * 180 + k * 20 + c] = src[i];
        }
        __syncthreads();

        for (int cl = 0; cl < 32; cl++) {
            int cin = c8 * 32 + cl;
            float sc = scb[cin];
            float bi = scb[256 + cin];
            float tap[9];
            #pragma unroll
            for (int k = 0; k < 9; k++) {
                int dy = k / 3 - 1, dx = k % 3 - 1;
                int yy = y + dy, x2 = xx + dx;
                bool in = (yy >= 0) && (yy < HH) && (x2 >= 0) && (x2 < WW);
                int yc = min(max(yy, 0), HH - 1);
                int xc = min(max(x2, 0), WW - 1);
                float v = xb[((size_t)cin * HH + yc) * WW + xc];
                float h = fmaxf(fmaf(v, sc, bi), 0.f);
                tap[k] = in ? h : 0.f;
            }
            const float* wrow = &wlds[cl * 180];
            #pragma unroll
            for (int k = 0; k < 9; k++) {
                float4 w0 = *(const float4*)(wrow + k * 20 + 0);
                float4 w1 = *(const float4*)(wrow + k * 20 + 4);
                float4 w2 = *(const float4*)(wrow + k * 20 + 8);
                float4 w3 = *(const float4*)(wrow + k * 20 + 12);
                float2 w4 = *(const float2*)(wrow + k * 20 + 16);
                float t = tap[k];
                acc[0]  = fmaf(t, w0.x, acc[0]);
                acc[1]  = fmaf(t, w0.y, acc[1]);
                acc[2]  = fmaf(t, w0.z, acc[2]);
                acc[3]  = fmaf(t, w0.w, acc[3]);
                acc[4]  = fmaf(t, w1.x, acc[4]);
                acc[5]  = fmaf(t, w1.y, acc[5]);
                acc[6]  = fmaf(t, w1.z, acc[6]);
                acc[7]  = fmaf(t, w1.w, acc[7]);
                acc[8]  = fmaf(t, w2.x, acc[8]);
                acc[9]  = fmaf(t, w2.y, acc[9]);
                acc[10] = fmaf(t, w2.z, acc[10]);
                acc[11] = fmaf(t, w2.w, acc[11]);
                acc[12] = fmaf(t, w3.x, acc[12]);
                acc[13] = fmaf(t, w3.y, acc[13]);
                acc[14] = fmaf(t, w3.z, acc[14]);
                acc[15] = fmaf(t, w3.w, acc[15]);
                acc[16] = fmaf(t, w4.x, acc[16]);
                acc[17] = fmaf(t, w4.y, acc[17]);
            }
        }
    }
    #pragma unroll
    for (int c = 0; c < OC; c++) {
        offs_out[(((b * NSPLIT + s) * OC + c) * HH + y) * WW + xx] = acc[c] + offb[s * OC + c];
    }
}

// K3: deformable conv, weights for each (s,k) staged through LDS
__global__ __launch_bounds__(256) void deform_kernel(const float* __restrict__ ht,    // ws+WS_HT
                                                     const float* __restrict__ offp,  // ws+WS_OFFS
                                                     const float* __restrict__ wdp,   // ws+WS_WDT
                                                     const float* __restrict__ bsum,  // ws+WS_BSUM
                                                     float* __restrict__ out) {
    __shared__ float vbuf[64 * 64];   // [cin][pixel] 16 KB
    __shared__ float wbuf[64 * 64];   // [cin][o]     16 KB
    int y = blockIdx.x;
    int b = blockIdx.y;
    int p = threadIdx.x & 63;                                   // pixel x
    int og = __builtin_amdgcn_readfirstlane(threadIdx.x >> 6);  // o-group / cin-group

    float acc[16];
    #pragma unroll
    for (int j = 0; j < 16; j++) acc[j] = bsum[og * 16 + j];

    const float* htb = ht + (size_t)b * HH * WW * CIN;

    for (int s = 0; s < NSPLIT; s++) {
        const float* htc = htb + s * COUT;   // channel offset within NHWC
        for (int k = 0; k < K2; k++) {
            __syncthreads();   // previous iteration's LDS reads complete

            // stage weights [cin][o] for this (s,k): contiguous 4096 floats
            const float* wsrc = wdp + (size_t)((s * 9 + k) * 64) * 64;
            #pragma unroll
            for (int r = 0; r < 4; r++) {
                int i = r * 1024 + threadIdx.x * 4;
                *(float4*)&wbuf[i] = *(const float4*)&wsrc[i];
            }

            // bilinear sample 16 channels for this pixel
            int dy = k / 3 - 1, dx = k % 3 - 1;
            float offy = offp[(((b * NSPLIT + s) * OC + 2 * k) * HH + y) * WW + p];
            float offx = offp[(((b * NSPLIT + s) * OC + 2 * k + 1) * HH + y) * WW + p];
            float py = (float)(y + dy) + offy;
            float px = (float)(p + dx) + offx;
            float y0f = floorf(py), x0f = floorf(px);
            float wy1 = py - y0f, wx1 = px - x0f;
            float wy0 = 1.f - wy1, wx0 = 1.f - wx1;
            int y0 = (int)y0f, x0 = (int)x0f;

            float v[16];
            #pragma unroll
            for (int j = 0; j < 16; j++) v[j] = 0.f;

            #pragma unroll
            for (int t = 0; t < 4; t++) {
                int yt = y0 + (t >> 1);
                int xt = x0 + (t & 1);
                float wt = ((t >> 1) ? wy1 : wy0) * ((t & 1) ? wx1 : wx0);
                bool valid = (yt >= 0) && (yt < HH) && (xt >= 0) && (xt < WW);
                wt = valid ? wt : 0.f;
                int yi = min(max(yt, 0), HH - 1);
                int xi = min(max(xt, 0), WW - 1);
                const float* srcp = htc + ((size_t)yi * WW + xi) * CIN + og * 16;
                #pragma unroll
                for (int q = 0; q < 4; q++) {
                    float4 f = *(const float4*)(srcp + q * 4);
                    v[q * 4 + 0] = fmaf(wt, f.x, v[q * 4 + 0]);
                    v[q * 4 + 1] = fmaf(wt, f.y, v[q * 4 + 1]);
                    v[q * 4 + 2] = fmaf(wt, f.z, v[q * 4 + 2]);
                    v[q * 4 + 3] = fmaf(wt, f.w, v[q * 4 + 3]);
                }
            }
            #pragma unroll
            for (int j = 0; j < 16; j++) vbuf[(og * 16 + j) * 64 + p] = v[j];
            __syncthreads();

            // GEMM: acc[o] += sum_cin vbuf[cin][p] * wbuf[cin][o]
            #pragma unroll 8
            for (int cin = 0; cin < COUT; cin++) {
                float vv = vbuf[cin * 64 + p];
                const float* wr = &wbuf[cin * 64 + og * 16];
                float4 q0 = *(const float4*)(wr + 0);
                float4 q1 = *(const float4*)(wr + 4);
                float4 q2 = *(const float4*)(wr + 8);
                float4 q3 = *(const float4*)(wr + 12);
                acc[0]  = fmaf(vv, q0.x, acc[0]);
                acc[1]  = fmaf(vv, q0.y, acc[1]);
                acc[2]  = fmaf(vv, q0.z, acc[2]);
                acc[3]  = fmaf(vv, q0.w, acc[3]);
                acc[4]  = fmaf(vv, q1.x, acc[4]);
                acc[5]  = fmaf(vv, q1.y, acc[5]);
                acc[6]  = fmaf(vv, q1.z, acc[6]);
                acc[7]  = fmaf(vv, q1.w, acc[7]);
                acc[8]  = fmaf(vv, q2.x, acc[8]);
                acc[9]  = fmaf(vv, q2.y, acc[9]);
                acc[10] = fmaf(vv, q2.z, acc[10]);
                acc[11] = fmaf(vv, q2.w, acc[11]);
                acc[12] = fmaf(vv, q3.x, acc[12]);
                acc[13] = fmaf(vv, q3.y, acc[13]);
                acc[14] = fmaf(vv, q3.z, acc[14]);
                acc[15] = fmaf(vv, q3.w, acc[15]);
            }
        }
    }
    #pragma unroll
    for (int j = 0; j < 16; j++) {
        int o = og * 16 + j;
        out[((b * COUT + o) * HH + y) * WW + p] = acc[j];
    }
}

extern "C" void kernel_launch(void* const* d_in, const int* in_sizes, int n_in,
                              void* d_out, int out_size, void* d_ws, size_t ws_size,
                              hipStream_t stream) {
    const float* x        = (const float*)d_in[0];
    const float* bn_gamma = (const float*)d_in[1];
    const float* bn_beta  = (const float*)d_in[2];
    const float* bn_mean  = (const float*)d_in[3];
    const float* bn_var   = (const float*)d_in[4];
    const float* offset_w = (const float*)d_in[5];
    const float* offset_b = (const float*)d_in[6];
    const float* dconv_w  = (const float*)d_in[7];
    const float* dconv_b  = (const float*)d_in[8];
    float* out = (float*)d_out;
    float* ws  = (float*)d_ws;

    prep_kernel<<<1, 256, 0, stream>>>(bn_gamma, bn_beta, bn_mean, bn_var, dconv_b, ws);
    wtrans_kernel<<<(WOT_SIZE + 255) / 256, 256, 0, stream>>>(dconv_w, offset_w, ws);
    bn_transpose_kernel<<<dim3(4, 64, 8), 256, 0, stream>>>(x, ws);
    offconv_kernel<<<dim3(16, 4, 8), 256, 0, stream>>>(x, offset_b,
                                                       ws + WS_SCALE, ws + WS_WOT, ws + WS_OFFS);
    deform_kernel<<<dim3(64, 8), 256, 0, stream>>>(ws + WS_HT, ws + WS_OFFS,
                                                   ws + WS_WDT, ws + WS_BSUM, out);
}

// Round 3
// 395.047 us; speedup vs baseline: 2.9353x; 1.6469x over previous
//
#include <hip/hip_runtime.h>

#define KK 3
#define CIN 256
#define COUT 64
#define NSPLIT 4
#define BB 8
#define HH 64
#define WW 64
#define K2 9
#define OC 18          // 2*K*K offset channels
#define EPS 1e-5f

typedef __attribute__((ext_vector_type(8))) short bf16x8;
typedef __attribute__((ext_vector_type(4))) float f32x4;

// ---- workspace layout (in floats) ----
#define WS_SCALE 0
#define WS_BIAS  256
#define WS_BSUM  512
#define WS_HT    1024
#define HT_SIZE  (BB*HH*WW*CIN)            // 8,388,608
#define WS_OFFS  (WS_HT + HT_SIZE)
#define OFFS_SIZE (BB*NSPLIT*OC*HH*WW)     // 2,359,296
#define WS_WDT   (WS_OFFS + OFFS_SIZE)
#define WDT_SIZE (NSPLIT*K2*COUT*COUT)     // 147,456 (stored as bf16, half the region)
#define WS_WOT   (WS_WDT + WDT_SIZE)
#define WOT_SIZE (NSPLIT*CIN*K2*OC)        // 663,552

// fp32 -> bf16 RNE
__device__ __host__ inline unsigned short f2bf(float f) {
    unsigned int u = __builtin_bit_cast(unsigned int, f);
    unsigned int r = (u + 0x7fffu + ((u >> 16) & 1u)) >> 16;
    return (unsigned short)r;
}

// K0: per-channel BN scale/bias + summed dconv bias
__global__ void prep_kernel(const float* __restrict__ g, const float* __restrict__ be,
                            const float* __restrict__ mn, const float* __restrict__ vr,
                            const float* __restrict__ db, float* __restrict__ ws) {
    int t = threadIdx.x;
    if (t < CIN) {
        float inv = 1.0f / sqrtf(vr[t] + EPS);
        float sc = g[t] * inv;
        ws[WS_SCALE + t] = sc;
        ws[WS_BIAS + t]  = be[t] - mn[t] * sc;
    }
    if (t < COUT) {
        float s = 0.f;
        for (int i = 0; i < NSPLIT; i++) s += db[i * COUT + t];
        ws[WS_BSUM + t] = s;
    }
}

// K0b: weight transposes
// wdT16[((s*9+k)*64 + o)*64 + cin] = bf16(dconv_w[s][o][cin][k])   (B-frag layout)
// woT2[((s*256+cin)*9+k)*18+c] = offset_w[((s*18+c)*256+cin)*9+k]
__global__ void wtrans_kernel(const float* __restrict__ dw, const float* __restrict__ ow,
                              float* __restrict__ ws) {
    int tid = blockIdx.x * blockDim.x + threadIdx.x;
    if (tid < WDT_SIZE) {
        int cin = tid & 63;
        int o = (tid >> 6) & 63;
        int k = (tid / 4096) % 9;
        int s = tid / 36864;
        ((unsigned short*)(ws + WS_WDT))[tid] = f2bf(dw[((s * COUT + o) * COUT + cin) * 9 + k]);
    }
    if (tid < WOT_SIZE) {
        int c = tid % OC;
        int k = (tid / OC) % 9;
        int cin = (tid / (9 * OC)) % CIN;
        int s = tid / (9 * OC * CIN);
        ws[WS_WOT + tid] = ow[((s * OC + c) * CIN + cin) * 9 + k];
    }
}

// K1: BN+ReLU and NCHW->NHWC transpose of h (for deform sampling)
__global__ __launch_bounds__(256) void bn_transpose_kernel(const float* __restrict__ x,
                                                           float* __restrict__ ws) {
    __shared__ float tile[64 * 65];
    int cg = blockIdx.x;          // channel group of 64
    int y  = blockIdx.y;
    int b  = blockIdx.z;
    int lane = threadIdx.x & 63;
    int grp  = threadIdx.x >> 6;
    #pragma unroll
    for (int i = 0; i < 16; i++) {
        int cl = grp * 16 + i;
        int c  = cg * 64 + cl;
        float v = x[((b * CIN + c) * HH + y) * WW + lane];
        float h = fmaxf(fmaf(v, ws[WS_SCALE + c], ws[WS_BIAS + c]), 0.f);
        tile[cl * 65 + lane] = h;
    }
    __syncthreads();
    #pragma unroll
    for (int i = 0; i < 16; i++) {
        int xx = grp * 16 + i;
        ws[WS_HT + ((b * HH + y) * WW + xx) * CIN + cg * 64 + lane] = tile[lane * 65 + xx];
    }
}

// K2: offset conv (256->18, 3x3, pad 1), weights staged through LDS
__global__ __launch_bounds__(256) void offconv_kernel(const float* __restrict__ x,
                                                      const float* __restrict__ offb,
                                                      const float* __restrict__ scb,   // ws+WS_SCALE
                                                      const float* __restrict__ woT2,  // ws+WS_WOT
                                                      float* __restrict__ offs_out) {  // ws+WS_OFFS
    __shared__ float wlds[32 * 9 * 20];
    int yblk = blockIdx.x;   // 16
    int s    = blockIdx.y;   // 4
    int b    = blockIdx.z;   // 8
    int lane = threadIdx.x & 63;
    int row  = threadIdx.x >> 6;
    int y = yblk * 4 + row;
    int xx = lane;

    float acc[OC];
    #pragma unroll
    for (int c = 0; c < OC; c++) acc[c] = 0.f;

    const float* xb = x + (size_t)b * CIN * HH * WW;

    for (int c8 = 0; c8 < 8; c8++) {
        __syncthreads();
        const float* src = woT2 + ((size_t)(s * CIN + c8 * 32)) * (9 * OC);
        for (int i = threadIdx.x; i < 32 * 9 * OC; i += 256) {
            int cl = i / (9 * OC);
            int r  = i % (9 * OC);
            int k  = r / OC;
            int c  = r % OC;
            wlds[cl * 180 + k * 20 + c] = src[i];
        }
        __syncthreads();

        for (int cl = 0; cl < 32; cl++) {
            int cin = c8 * 32 + cl;
            float sc = scb[cin];
            float bi = scb[256 + cin];
            float tap[9];
            #pragma unroll
            for (int k = 0; k < 9; k++) {
                int dy = k / 3 - 1, dx = k % 3 - 1;
                int yy = y + dy, x2 = xx + dx;
                bool in = (yy >= 0) && (yy < HH) && (x2 >= 0) && (x2 < WW);
                int yc = min(max(yy, 0), HH - 1);
                int xc = min(max(x2, 0), WW - 1);
                float v = xb[((size_t)cin * HH + yc) * WW + xc];
                float h = fmaxf(fmaf(v, sc, bi), 0.f);
                tap[k] = in ? h : 0.f;
            }
            const float* wrow = &wlds[cl * 180];
            #pragma unroll
            for (int k = 0; k < 9; k++) {
                float4 w0 = *(const float4*)(wrow + k * 20 + 0);
                float4 w1 = *(const float4*)(wrow + k * 20 + 4);
                float4 w2 = *(const float4*)(wrow + k * 20 + 8);
                float4 w3 = *(const float4*)(wrow + k * 20 + 12);
                float2 w4 = *(const float2*)(wrow + k * 20 + 16);
                float t = tap[k];
                acc[0]  = fmaf(t, w0.x, acc[0]);
                acc[1]  = fmaf(t, w0.y, acc[1]);
                acc[2]  = fmaf(t, w0.z, acc[2]);
                acc[3]  = fmaf(t, w0.w, acc[3]);
                acc[4]  = fmaf(t, w1.x, acc[4]);
                acc[5]  = fmaf(t, w1.y, acc[5]);
                acc[6]  = fmaf(t, w1.z, acc[6]);
                acc[7]  = fmaf(t, w1.w, acc[7]);
                acc[8]  = fmaf(t, w2.x, acc[8]);
                acc[9]  = fmaf(t, w2.y, acc[9]);
                acc[10] = fmaf(t, w2.z, acc[10]);
                acc[11] = fmaf(t, w2.w, acc[11]);
                acc[12] = fmaf(t, w3.x, acc[12]);
                acc[13] = fmaf(t, w3.y, acc[13]);
                acc[14] = fmaf(t, w3.z, acc[14]);
                acc[15] = fmaf(t, w3.w, acc[15]);
                acc[16] = fmaf(t, w4.x, acc[16]);
                acc[17] = fmaf(t, w4.y, acc[17]);
            }
        }
    }
    #pragma unroll
    for (int c = 0; c < OC; c++) {
        offs_out[(((b * NSPLIT + s) * OC + c) * HH + y) * WW + xx] = acc[c] + offb[s * OC + c];
    }
}

// K3: deformable conv via bf16 MFMA. Block = one (b,y): 64 px x 64 out, K=64 per (s,k).
__global__ __launch_bounds__(256) void deform_kernel(const float* __restrict__ ht,    // fp32 NHWC
                                                     const float* __restrict__ offp,
                                                     const unsigned short* __restrict__ wdT, // bf16 [s][k][o][cin]
                                                     const float* __restrict__ bsum,
                                                     float* __restrict__ out) {
    __shared__ unsigned short vbufS[64 * 72];  // [px][cin] bf16, pad 8
    __shared__ unsigned short wbufS[64 * 72];  // [o][cin]  bf16, pad 8
    __shared__ float outT[64 * 68];            // [o][px]   fp32, pad 4

    int tid = threadIdx.x;
    // XCD-aware swizzle: dispatch-order % 8 -> b, so each XCD's L2 holds one image
    int bid = blockIdx.x + 64 * blockIdx.y;
    int b = bid & 7;
    int y = bid >> 3;

    int p  = tid & 63;      // pixel (sampling role)
    int og = tid >> 6;      // channel-group (sampling) == wave id (mfma)
    int l  = tid & 63;      // lane
    int lm = l & 15;        // frag row/col
    int lk = l >> 4;        // frag k-group
    int w  = og;

    f32x4 acc[4];
    #pragma unroll
    for (int nt = 0; nt < 4; nt++) {
        float bs = bsum[nt * 16 + lm];
        acc[nt] = (f32x4){bs, bs, bs, bs};
    }

    const float* htb = ht + (size_t)b * HH * WW * CIN;

    for (int s = 0; s < NSPLIT; s++) {
        const float* htc = htb + s * COUT;
        for (int k = 0; k < K2; k++) {
            // (1) issue weight loads early (32B/thread, contiguous)
            const unsigned short* wsrc = wdT + (size_t)((s * 9 + k) * 64) * 64;
            bf16x8 wr0 = *(const bf16x8*)(wsrc + tid * 16);
            bf16x8 wr1 = *(const bf16x8*)(wsrc + tid * 16 + 8);

            // (2) bilinear sample 16 channels for pixel p (fp32)
            int dy = k / 3 - 1, dx = k % 3 - 1;
            float offy = offp[(((b * NSPLIT + s) * OC + 2 * k) * HH + y) * WW + p];
            float offx = offp[(((b * NSPLIT + s) * OC + 2 * k + 1) * HH + y) * WW + p];
            float py = (float)(y + dy) + offy;
            float px_ = (float)(p + dx) + offx;
            float y0f = floorf(py), x0f = floorf(px_);
            float wy1 = py - y0f, wx1 = px_ - x0f;
            float wy0 = 1.f - wy1, wx0 = 1.f - wx1;
            int y0 = (int)y0f, x0 = (int)x0f;

            float v[16];
            #pragma unroll
            for (int j = 0; j < 16; j++) v[j] = 0.f;

            #pragma unroll
            for (int t = 0; t < 4; t++) {
                int yt = y0 + (t >> 1);
                int xt = x0 + (t & 1);
                float wt = ((t >> 1) ? wy1 : wy0) * ((t & 1) ? wx1 : wx0);
                bool valid = (yt >= 0) && (yt < HH) && (xt >= 0) && (xt < WW);
                wt = valid ? wt : 0.f;
                int yi = min(max(yt, 0), HH - 1);
                int xi = min(max(xt, 0), WW - 1);
                const float* srcp = htc + ((size_t)yi * WW + xi) * CIN + og * 16;
                #pragma unroll
                for (int q = 0; q < 4; q++) {
                    float4 f = *(const float4*)(srcp + q * 4);
                    v[q * 4 + 0] = fmaf(wt, f.x, v[q * 4 + 0]);
                    v[q * 4 + 1] = fmaf(wt, f.y, v[q * 4 + 1]);
                    v[q * 4 + 2] = fmaf(wt, f.z, v[q * 4 + 2]);
                    v[q * 4 + 3] = fmaf(wt, f.w, v[q * 4 + 3]);
                }
            }
            // convert to bf16 fragments
            bf16x8 v0, v1;
            #pragma unroll
            for (int j = 0; j < 8; j++) {
                v0[j] = (short)f2bf(v[j]);
                v1[j] = (short)f2bf(v[j + 8]);
            }

            __syncthreads();   // previous iteration's MFMA LDS reads complete
            // (3) write LDS
            *(bf16x8*)(&vbufS[p * 72 + og * 16])     = v0;
            *(bf16x8*)(&vbufS[p * 72 + og * 16 + 8]) = v1;
            {
                int wo = tid >> 2, wpart = tid & 3;
                *(bf16x8*)(&wbufS[wo * 72 + wpart * 16])     = wr0;
                *(bf16x8*)(&wbufS[wo * 72 + wpart * 16 + 8]) = wr1;
            }
            __syncthreads();

            // (4) MFMA: D[px][o] += V[px][cin] * W[cin][o]
            #pragma unroll
            for (int ks = 0; ks < 2; ks++) {
                bf16x8 a = *(const bf16x8*)(&vbufS[(w * 16 + lm) * 72 + ks * 32 + lk * 8]);
                #pragma unroll
                for (int nt = 0; nt < 4; nt++) {
                    bf16x8 bb = *(const bf16x8*)(&wbufS[(nt * 16 + lm) * 72 + ks * 32 + lk * 8]);
                    acc[nt] = __builtin_amdgcn_mfma_f32_16x16x32_bf16(a, bb, acc[nt], 0, 0, 0);
                }
            }
        }
    }

    // epilogue: transpose via LDS, coalesced row stores
    #pragma unroll
    for (int nt = 0; nt < 4; nt++) {
        *(f32x4*)(&outT[(nt * 16 + lm) * 68 + w * 16 + lk * 4]) = acc[nt];
    }
    __syncthreads();
    {
        int o = tid >> 2, xp = (tid & 3) * 16;
        float* dst = out + (((size_t)(b * COUT + o)) * HH + y) * WW + xp;
        #pragma unroll
        for (int q = 0; q < 4; q++) {
            *(float4*)(dst + q * 4) = *(const float4*)(&outT[o * 68 + xp + q * 4]);
        }
    }
}

extern "C" void kernel_launch(void* const* d_in, const int* in_sizes, int n_in,
                              void* d_out, int out_size, void* d_ws, size_t ws_size,
                              hipStream_t stream) {
    const float* x        = (const float*)d_in[0];
    const float* bn_gamma = (const float*)d_in[1];
    const float* bn_beta  = (const float*)d_in[2];
    const float* bn_mean  = (const float*)d_in[3];
    const float* bn_var   = (const float*)d_in[4];
    const float* offset_w = (const float*)d_in[5];
    const float* offset_b = (const float*)d_in[6];
    const float* dconv_w  = (const float*)d_in[7];
    const float* dconv_b  = (const float*)d_in[8];
    float* out = (float*)d_out;
    float* ws  = (float*)d_ws;

    prep_kernel<<<1, 256, 0, stream>>>(bn_gamma, bn_beta, bn_mean, bn_var, dconv_b, ws);
    wtrans_kernel<<<(WOT_SIZE + 255) / 256, 256, 0, stream>>>(dconv_w, offset_w, ws);
    bn_transpose_kernel<<<dim3(4, 64, 8), 256, 0, stream>>>(x, ws);
    offconv_kernel<<<dim3(16, 4, 8), 256, 0, stream>>>(x, offset_b,
                                                       ws + WS_SCALE, ws + WS_WOT, ws + WS_OFFS);
    deform_kernel<<<dim3(64, 8), 256, 0, stream>>>(ws + WS_HT, ws + WS_OFFS,
                                                   (const unsigned short*)(ws + WS_WDT),
                                                   ws + WS_BSUM, out);
}

// Round 4
// 128.793 us; speedup vs baseline: 9.0036x; 3.0673x over previous
//
#include <hip/hip_runtime.h>

#define KK 3
#define CIN 256
#define COUT 64
#define NSPLIT 4
#define BB 8
#define HH 64
#define WW 64
#define K2 9
#define OC 18          // 2*K*K offset channels
#define EPS 1e-5f

typedef __attribute__((ext_vector_type(8))) short bf16x8;
typedef __attribute__((ext_vector_type(4))) float f32x4;

// ---- workspace layout (in floats) ----
#define WS_SCALE 0
#define WS_BIAS  256
#define WS_BSUM  512
#define WS_HBF   1024
#define HBF_FLOATS (BB*HH*WW*CIN/2)        // bf16 h, NHWC: 4,194,304 floats
#define WS_OFFS  (WS_HBF + HBF_FLOATS)
#define OFFS_SIZE (BB*NSPLIT*OC*HH*WW)     // 2,359,296
#define WS_WDT   (WS_OFFS + OFFS_SIZE)     // bf16 [s][k][o][cin]: 147,456 shorts
#define WS_WOB   (WS_WDT + NSPLIT*K2*COUT*COUT/2)
#define WOB_ELEMS (K2*80*CIN)              // bf16 [k][sc(80)][cin]: 184,320 shorts

// fp32 -> bf16 RNE
__device__ __host__ inline unsigned short f2bf(float f) {
    unsigned int u = __builtin_bit_cast(unsigned int, f);
    unsigned int r = (u + 0x7fffu + ((u >> 16) & 1u)) >> 16;
    return (unsigned short)r;
}
__device__ inline float bf2f(unsigned short u) {
    return __builtin_bit_cast(float, (unsigned int)u << 16);
}

// K0: per-channel BN scale/bias + summed dconv bias
__global__ void prep_kernel(const float* __restrict__ g, const float* __restrict__ be,
                            const float* __restrict__ mn, const float* __restrict__ vr,
                            const float* __restrict__ db, float* __restrict__ ws) {
    int t = threadIdx.x;
    if (t < CIN) {
        float inv = 1.0f / sqrtf(vr[t] + EPS);
        float sc = g[t] * inv;
        ws[WS_SCALE + t] = sc;
        ws[WS_BIAS + t]  = be[t] - mn[t] * sc;
    }
    if (t < COUT) {
        float s = 0.f;
        for (int i = 0; i < NSPLIT; i++) s += db[i * COUT + t];
        ws[WS_BSUM + t] = s;
    }
}

// K0b: weight transposes (both bf16)
// wdT[((s*9+k)*64 + o)*64 + cin]          (deform B-frag layout)
// woB[(k*80 + sc)*256 + cin], sc=s*18+c, zero for sc>=72   (offconv B-frag layout)
__global__ void wtrans_kernel(const float* __restrict__ dw, const float* __restrict__ ow,
                              float* __restrict__ ws) {
    int tid = blockIdx.x * blockDim.x + threadIdx.x;
    if (tid < NSPLIT * K2 * COUT * COUT) {
        int cin = tid & 63;
        int o = (tid >> 6) & 63;
        int k = (tid / 4096) % 9;
        int s = tid / 36864;
        ((unsigned short*)(ws + WS_WDT))[tid] = f2bf(dw[((s * COUT + o) * COUT + cin) * 9 + k]);
    }
    if (tid < WOB_ELEMS) {
        int cin = tid & 255;
        int sc = (tid >> 8) % 80;
        int k = tid / 20480;
        unsigned short v = 0;
        if (sc < 72) {
            int s = sc / 18, c = sc % 18;
            v = f2bf(ow[((s * OC + c) * CIN + cin) * 9 + k]);
        }
        ((unsigned short*)(ws + WS_WOB))[tid] = v;
    }
}

// K1: BN+ReLU, NCHW -> bf16 NHWC
__global__ __launch_bounds__(256) void bn_transpose_kernel(const float* __restrict__ x,
                                                           const float* __restrict__ scb,
                                                           unsigned short* __restrict__ hbf) {
    __shared__ float tile[64 * 65];
    int cg = blockIdx.x;          // channel group of 64
    int y  = blockIdx.y;
    int b  = blockIdx.z;
    int lane = threadIdx.x & 63;
    int grp  = threadIdx.x >> 6;
    #pragma unroll
    for (int i = 0; i < 16; i++) {
        int cl = grp * 16 + i;
        int c  = cg * 64 + cl;
        float v = x[((b * CIN + c) * HH + y) * WW + lane];
        float h = fmaxf(fmaf(v, scb[c], scb[256 + c]), 0.f);
        tile[cl * 65 + lane] = h;
    }
    __syncthreads();
    int cpair = threadIdx.x & 31;
    int pxg   = threadIdx.x >> 5;
    #pragma unroll
    for (int i = 0; i < 8; i++) {
        int px = pxg * 8 + i;
        unsigned int u0 = f2bf(tile[(cpair * 2) * 65 + px]);
        unsigned int u1 = f2bf(tile[(cpair * 2 + 1) * 65 + px]);
        *(unsigned int*)&hbf[((size_t)(b * HH + y) * WW + px) * CIN + cg * 64 + cpair * 2] =
            u0 | (u1 << 16);
    }
}

// K2: offset conv via bf16 MFMA. Block = (b,y): M=64 px, N=80 (4 splits x 18, padded), K=256/tap.
__global__ __launch_bounds__(256) void offconv_kernel(const unsigned short* __restrict__ hbf,
                                                      const float* __restrict__ offb,
                                                      const unsigned short* __restrict__ woB,
                                                      float* __restrict__ offs_out) {
    __shared__ unsigned short wlds[80 * 264];   // [sc][cin], cin padded 256->264
    int tid = threadIdx.x;
    int bid = blockIdx.x + 64 * blockIdx.y;     // XCD swizzle: b = bid & 7
    int b = bid & 7;
    int y = bid >> 3;
    int w  = tid >> 6;
    int l  = tid & 63;
    int lm = l & 15, lk = l >> 4;
    int px = w * 16 + lm;

    f32x4 acc[5];
    #pragma unroll
    for (int nt = 0; nt < 5; nt++) {
        int sc = nt * 16 + lm;
        float ob = (sc < 72) ? offb[sc] : 0.f;
        acc[nt] = (f32x4){ob, ob, ob, ob};
    }
    const unsigned short* hb = hbf + (size_t)b * HH * WW * CIN;
    const bf16x8 zero = {};

    for (int k = 0; k < 9; k++) {
        int dy = k / 3 - 1, dx = k % 3 - 1;
        int ry = y + dy;
        if ((unsigned)ry >= (unsigned)HH) continue;   // uniform: whole tap contributes zero
        __syncthreads();   // previous tap's B reads complete
        const unsigned short* src = woB + (size_t)k * 80 * 256;
        #pragma unroll
        for (int t = 0; t < 10; t++) {
            int idx = tid + t * 256;          // 16B chunk id (2560 total)
            int sc = idx >> 5;
            int co = (idx & 31) * 8;
            *(bf16x8*)&wlds[sc * 264 + co] = *(const bf16x8*)&src[sc * 256 + co];
        }
        __syncthreads();

        int rx = px + dx;
        bool vx = (unsigned)rx < (unsigned)WW;
        const unsigned short* arow = hb + ((size_t)ry * WW + rx) * CIN + lk * 8;
        #pragma unroll
        for (int kt = 0; kt < 8; kt++) {
            bf16x8 a = vx ? *(const bf16x8*)(arow + kt * 32) : zero;
            #pragma unroll
            for (int nt = 0; nt < 5; nt++) {
                bf16x8 bb = *(const bf16x8*)&wlds[(nt * 16 + lm) * 264 + kt * 32 + lk * 8];
                acc[nt] = __builtin_amdgcn_mfma_f32_16x16x32_bf16(a, bb, acc[nt], 0, 0, 0);
            }
        }
    }

    // D[row=px=w*16+lk*4+j][col=sc=nt*16+lm]; px fastest dim -> float4 stores
    #pragma unroll
    for (int nt = 0; nt < 5; nt++) {
        int sc = nt * 16 + lm;
        if (sc < 72) {
            float4 v = {acc[nt][0], acc[nt][1], acc[nt][2], acc[nt][3]};
            *(float4*)&offs_out[((size_t)(b * 72 + sc) * HH + y) * WW + w * 16 + lk * 4] = v;
        }
    }
}

// K3: deformable conv via bf16 MFMA, sampling from bf16 NHWC hbf
__global__ __launch_bounds__(256) void deform_kernel(const unsigned short* __restrict__ hbf,
                                                     const float* __restrict__ offp,
                                                     const unsigned short* __restrict__ wdT,
                                                     const float* __restrict__ bsum,
                                                     float* __restrict__ out) {
    __shared__ unsigned short vbufS[64 * 72];  // [px][cin] bf16, pad 8
    __shared__ unsigned short wbufS[64 * 72];  // [o][cin]  bf16, pad 8
    __shared__ float outT[64 * 68];            // [o][px]   fp32, pad 4

    int tid = threadIdx.x;
    int bid = blockIdx.x + 64 * blockIdx.y;
    int b = bid & 7;
    int y = bid >> 3;

    int p  = tid & 63;      // pixel (sampling role)
    int og = tid >> 6;      // channel-group (sampling) == wave id (mfma)
    int l  = tid & 63;
    int lm = l & 15;
    int lk = l >> 4;
    int w  = og;

    f32x4 acc[4];
    #pragma unroll
    for (int nt = 0; nt < 4; nt++) {
        float bs = bsum[nt * 16 + lm];
        acc[nt] = (f32x4){bs, bs, bs, bs};
    }

    const unsigned short* hb = hbf + (size_t)b * HH * WW * CIN;

    for (int s = 0; s < NSPLIT; s++) {
        const unsigned short* htc = hb + s * COUT + og * 16;
        for (int k = 0; k < K2; k++) {
            // (1) issue weight loads early (32B/thread, contiguous)
            const unsigned short* wsrc = wdT + (size_t)((s * 9 + k) * 64) * 64;
            bf16x8 wr0 = *(const bf16x8*)(wsrc + tid * 16);
            bf16x8 wr1 = *(const bf16x8*)(wsrc + tid * 16 + 8);

            // (2) bilinear sample 16 channels for pixel p
            int dy = k / 3 - 1, dx = k % 3 - 1;
            float offy = offp[(((b * NSPLIT + s) * OC + 2 * k) * HH + y) * WW + p];
            float offx = offp[(((b * NSPLIT + s) * OC + 2 * k + 1) * HH + y) * WW + p];
            float py = (float)(y + dy) + offy;
            float px_ = (float)(p + dx) + offx;
            float y0f = floorf(py), x0f = floorf(px_);
            float wy1 = py - y0f, wx1 = px_ - x0f;
            float wy0 = 1.f - wy1, wx0 = 1.f - wx1;
            int y0 = (int)y0f, x0 = (int)x0f;

            float v[16];
            #pragma unroll
            for (int j = 0; j < 16; j++) v[j] = 0.f;

            #pragma unroll
            for (int t = 0; t < 4; t++) {
                int yt = y0 + (t >> 1);
                int xt = x0 + (t & 1);
                float wt = ((t >> 1) ? wy1 : wy0) * ((t & 1) ? wx1 : wx0);
                bool valid = (yt >= 0) && (yt < HH) && (xt >= 0) && (xt < WW);
                wt = valid ? wt : 0.f;
                int yi = min(max(yt, 0), HH - 1);
                int xi = min(max(xt, 0), WW - 1);
                const unsigned short* srcp = htc + ((size_t)yi * WW + xi) * CIN;
                bf16x8 f0 = *(const bf16x8*)(srcp);
                bf16x8 f1 = *(const bf16x8*)(srcp + 8);
                #pragma unroll
                for (int j = 0; j < 8; j++) {
                    v[j]     = fmaf(wt, bf2f((unsigned short)f0[j]), v[j]);
                    v[j + 8] = fmaf(wt, bf2f((unsigned short)f1[j]), v[j + 8]);
                }
            }
            // convert to bf16 fragments
            bf16x8 v0, v1;
            #pragma unroll
            for (int j = 0; j < 8; j++) {
                v0[j] = (short)f2bf(v[j]);
                v1[j] = (short)f2bf(v[j + 8]);
            }

            __syncthreads();   // previous iteration's MFMA LDS reads complete
            *(bf16x8*)(&vbufS[p * 72 + og * 16])     = v0;
            *(bf16x8*)(&vbufS[p * 72 + og * 16 + 8]) = v1;
            {
                int wo = tid >> 2, wpart = tid & 3;
                *(bf16x8*)(&wbufS[wo * 72 + wpart * 16])     = wr0;
                *(bf16x8*)(&wbufS[wo * 72 + wpart * 16 + 8]) = wr1;
            }
            __syncthreads();

            // (4) MFMA: D[px][o] += V[px][cin] * W^T[o][cin]
            #pragma unroll
            for (int ks = 0; ks < 2; ks++) {
                bf16x8 a = *(const bf16x8*)(&vbufS[(w * 16 + lm) * 72 + ks * 32 + lk * 8]);
                #pragma unroll
                for (int nt = 0; nt < 4; nt++) {
                    bf16x8 bb = *(const bf16x8*)(&wbufS[(nt * 16 + lm) * 72 + ks * 32 + lk * 8]);
                    acc[nt] = __builtin_amdgcn_mfma_f32_16x16x32_bf16(a, bb, acc[nt], 0, 0, 0);
                }
            }
        }
    }

    // epilogue: transpose via LDS, coalesced row stores
    #pragma unroll
    for (int nt = 0; nt < 4; nt++) {
        *(f32x4*)(&outT[(nt * 16 + lm) * 68 + w * 16 + lk * 4]) = acc[nt];
    }
    __syncthreads();
    {
        int o = tid >> 2, xp = (tid & 3) * 16;
        float* dst = out + (((size_t)(b * COUT + o)) * HH + y) * WW + xp;
        #pragma unroll
        for (int q = 0; q < 4; q++) {
            *(float4*)(dst + q * 4) = *(const float4*)(&outT[o * 68 + xp + q * 4]);
        }
    }
}

extern "C" void kernel_launch(void* const* d_in, const int* in_sizes, int n_in,
                              void* d_out, int out_size, void* d_ws, size_t ws_size,
                              hipStream_t stream) {
    const float* x        = (const float*)d_in[0];
    const float* bn_gamma = (const float*)d_in[1];
    const float* bn_beta  = (const float*)d_in[2];
    const float* bn_mean  = (const float*)d_in[3];
    const float* bn_var   = (const float*)d_in[4];
    const float* offset_w = (const float*)d_in[5];
    const float* offset_b = (const float*)d_in[6];
    const float* dconv_w  = (const float*)d_in[7];
    const float* dconv_b  = (const float*)d_in[8];
    float* out = (float*)d_out;
    float* ws  = (float*)d_ws;

    unsigned short* hbf = (unsigned short*)(ws + WS_HBF);

    prep_kernel<<<1, 256, 0, stream>>>(bn_gamma, bn_beta, bn_mean, bn_var, dconv_b, ws);
    wtrans_kernel<<<(WOB_ELEMS + 255) / 256, 256, 0, stream>>>(dconv_w, offset_w, ws);
    bn_transpose_kernel<<<dim3(4, 64, 8), 256, 0, stream>>>(x, ws, hbf);
    offconv_kernel<<<dim3(64, 8), 256, 0, stream>>>(hbf, offset_b,
                                                    (const unsigned short*)(ws + WS_WOB),
                                                    ws + WS_OFFS);
    deform_kernel<<<dim3(64, 8), 256, 0, stream>>>(hbf, ws + WS_OFFS,
                                                   (const unsigned short*)(ws + WS_WDT),
                                                   ws + WS_BSUM, out);
}

// Round 5
// 126.814 us; speedup vs baseline: 9.1441x; 1.0156x over previous
//
#include <hip/hip_runtime.h>

#define KK 3
#define CIN 256
#define COUT 64
#define NSPLIT 4
#define BB 8
#define HH 64
#define WW 64
#define K2 9
#define OC 18          // 2*K*K offset channels
#define EPS 1e-5f

typedef __attribute__((ext_vector_type(8))) short bf16x8;
typedef __attribute__((ext_vector_type(4))) float f32x4;
typedef __attribute__((ext_vector_type(4))) unsigned int u32x4;

// ---- workspace layout (in floats) ----
#define WS_SCALE 0
#define WS_BIAS  256
#define WS_BSUM  512
#define WS_HBF   1024
#define HBF_FLOATS (BB*HH*WW*CIN/2)        // bf16 h, NHWC: 4,194,304 floats
#define WS_OFFS  (WS_HBF + HBF_FLOATS)
#define OFFS_SIZE (BB*72*HH*WW)            // 2,359,296
#define WS_WDT   (WS_OFFS + OFFS_SIZE)     // bf16 [s][k][o][cin]: 147,456 shorts
#define WS_WOB   (WS_WDT + NSPLIT*K2*COUT*COUT/2)
#define WOB_ELEMS (K2*80*CIN)              // bf16 [k][sc(80)][cin]: 184,320 shorts

// fp32 -> bf16 RNE
__device__ __host__ inline unsigned short f2bf(float f) {
    unsigned int u = __builtin_bit_cast(unsigned int, f);
    unsigned int r = (u + 0x7fffu + ((u >> 16) & 1u)) >> 16;
    return (unsigned short)r;
}
__device__ inline float bf2f(unsigned short u) {
    return __builtin_bit_cast(float, (unsigned int)u << 16);
}

// K0: per-channel BN scale/bias + summed dconv bias
__global__ void prep_kernel(const float* __restrict__ g, const float* __restrict__ be,
                            const float* __restrict__ mn, const float* __restrict__ vr,
                            const float* __restrict__ db, float* __restrict__ ws) {
    int t = threadIdx.x;
    if (t < CIN) {
        float inv = 1.0f / sqrtf(vr[t] + EPS);
        float sc = g[t] * inv;
        ws[WS_SCALE + t] = sc;
        ws[WS_BIAS + t]  = be[t] - mn[t] * sc;
    }
    if (t < COUT) {
        float s = 0.f;
        for (int i = 0; i < NSPLIT; i++) s += db[i * COUT + t];
        ws[WS_BSUM + t] = s;
    }
}

// K0b: weight transposes (both bf16)
__global__ void wtrans_kernel(const float* __restrict__ dw, const float* __restrict__ ow,
                              float* __restrict__ ws) {
    int tid = blockIdx.x * blockDim.x + threadIdx.x;
    if (tid < NSPLIT * K2 * COUT * COUT) {
        int cin = tid & 63;
        int o = (tid >> 6) & 63;
        int k = (tid / 4096) % 9;
        int s = tid / 36864;
        ((unsigned short*)(ws + WS_WDT))[tid] = f2bf(dw[((s * COUT + o) * COUT + cin) * 9 + k]);
    }
    if (tid < WOB_ELEMS) {
        int cin = tid & 255;
        int sc = (tid >> 8) % 80;
        int k = tid / 20480;
        unsigned short v = 0;
        if (sc < 72) {
            int s = sc / 18, c = sc % 18;
            v = f2bf(ow[((s * OC + c) * CIN + cin) * 9 + k]);
        }
        ((unsigned short*)(ws + WS_WOB))[tid] = v;
    }
}

// K1: BN+ReLU, NCHW -> bf16 NHWC
__global__ __launch_bounds__(256) void bn_transpose_kernel(const float* __restrict__ x,
                                                           const float* __restrict__ scb,
                                                           unsigned short* __restrict__ hbf) {
    __shared__ float tile[64 * 65];
    int cg = blockIdx.x;
    int y  = blockIdx.y;
    int b  = blockIdx.z;
    int lane = threadIdx.x & 63;
    int grp  = threadIdx.x >> 6;
    #pragma unroll
    for (int i = 0; i < 16; i++) {
        int cl = grp * 16 + i;
        int c  = cg * 64 + cl;
        float v = x[((b * CIN + c) * HH + y) * WW + lane];
        float h = fmaxf(fmaf(v, scb[c], scb[256 + c]), 0.f);
        tile[cl * 65 + lane] = h;
    }
    __syncthreads();
    int cpair = threadIdx.x & 31;
    int pxg   = threadIdx.x >> 5;
    #pragma unroll
    for (int i = 0; i < 8; i++) {
        int px = pxg * 8 + i;
        unsigned int u0 = f2bf(tile[(cpair * 2) * 65 + px]);
        unsigned int u1 = f2bf(tile[(cpair * 2 + 1) * 65 + px]);
        *(unsigned int*)&hbf[((size_t)(b * HH + y) * WW + px) * CIN + cg * 64 + cpair * 2] =
            u0 | (u1 << 16);
    }
}

// K2: offset conv via bf16 MFMA. Block = (b,y): M=64 px, N=80, K=256/tap.
__global__ __launch_bounds__(256) void offconv_kernel(const unsigned short* __restrict__ hbf,
                                                      const float* __restrict__ offb,
                                                      const unsigned short* __restrict__ woB,
                                                      float* __restrict__ offs_out) {
    __shared__ unsigned short wlds[80 * 264];
    int tid = threadIdx.x;
    int bid = blockIdx.x + 64 * blockIdx.y;
    int b = bid & 7;
    int y = bid >> 3;
    int w  = tid >> 6;
    int l  = tid & 63;
    int lm = l & 15, lk = l >> 4;
    int px = w * 16 + lm;

    f32x4 acc[5];
    #pragma unroll
    for (int nt = 0; nt < 5; nt++) {
        int sc = nt * 16 + lm;
        float ob = (sc < 72) ? offb[sc] : 0.f;
        acc[nt] = (f32x4){ob, ob, ob, ob};
    }
    const unsigned short* hb = hbf + (size_t)b * HH * WW * CIN;
    const bf16x8 zero = {};

    for (int k = 0; k < 9; k++) {
        int dy = k / 3 - 1, dx = k % 3 - 1;
        int ry = y + dy;
        if ((unsigned)ry >= (unsigned)HH) continue;
        __syncthreads();
        const unsigned short* src = woB + (size_t)k * 80 * 256;
        #pragma unroll
        for (int t = 0; t < 10; t++) {
            int idx = tid + t * 256;
            int sc = idx >> 5;
            int co = (idx & 31) * 8;
            *(bf16x8*)&wlds[sc * 264 + co] = *(const bf16x8*)&src[sc * 256 + co];
        }
        __syncthreads();

        int rx = px + dx;
        bool vx = (unsigned)rx < (unsigned)WW;
        const unsigned short* arow = hb + ((size_t)ry * WW + rx) * CIN + lk * 8;
        #pragma unroll
        for (int kt = 0; kt < 8; kt++) {
            bf16x8 a = vx ? *(const bf16x8*)(arow + kt * 32) : zero;
            #pragma unroll
            for (int nt = 0; nt < 5; nt++) {
                bf16x8 bb = *(const bf16x8*)&wlds[(nt * 16 + lm) * 264 + kt * 32 + lk * 8];
                acc[nt] = __builtin_amdgcn_mfma_f32_16x16x32_bf16(a, bb, acc[nt], 0, 0, 0);
            }
        }
    }

    #pragma unroll
    for (int nt = 0; nt < 5; nt++) {
        int sc = nt * 16 + lm;
        if (sc < 72) {
            float4 v = {acc[nt][0], acc[nt][1], acc[nt][2], acc[nt][3]};
            *(float4*)&offs_out[((size_t)(b * 72 + sc) * HH + y) * WW + w * 16 + lk * 4] = v;
        }
    }
}

// K3: deformable conv via bf16 MFMA with COOPERATIVE gathers.
// Per (s,k): 256 threads build tbl[pixel][corner]={offset,weight}; each wave then
// gathers 8 lanes per (pixel,corner) (128B contiguous) -> 16 segments/instr vs 64.
__global__ __launch_bounds__(256) void deform_kernel(const unsigned short* __restrict__ hbf,
                                                     const float* __restrict__ offp,
                                                     const unsigned short* __restrict__ wdT,
                                                     const float* __restrict__ bsum,
                                                     float* __restrict__ out) {
    __shared__ unsigned short vbufS[64 * 72];  // [px][cin] bf16, pad 8
    __shared__ unsigned short wbufS[64 * 72];  // [o][cin]  bf16, pad 8
    __shared__ float outT[64 * 68];            // [o][px]   fp32, pad 4
    __shared__ int tblI[64 * 8];               // [px][corner] {off, wt-bits}

    int tid = threadIdx.x;
    int bid = blockIdx.x + 64 * blockIdx.y;
    int b = bid & 7;
    int y = bid >> 3;

    int l  = tid & 63;
    int w  = tid >> 6;      // wave id
    int lm = l & 15;
    int lk = l >> 4;
    int pA = tid >> 2;      // phase-A pixel (0..63)
    int cA = tid & 3;       // phase-A corner
    int sub = l >> 3;       // gather: pixel-within-group (0..7)
    int ch  = (l & 7) * 8;  // gather: channel slice base

    f32x4 acc[4];
    #pragma unroll
    for (int nt = 0; nt < 4; nt++) {
        float bs = bsum[nt * 16 + lm];
        acc[nt] = (f32x4){bs, bs, bs, bs};
    }

    const unsigned short* hb = hbf + (size_t)b * HH * WW * CIN;

    for (int s = 0; s < NSPLIT; s++) {
        for (int k = 0; k < K2; k++) {
            // (0) issue weight loads early (32B/thread, contiguous)
            const unsigned short* wsrc = wdT + (size_t)((s * 9 + k) * 64) * 64;
            bf16x8 wr0 = *(const bf16x8*)(wsrc + tid * 16);
            bf16x8 wr1 = *(const bf16x8*)(wsrc + tid * 16 + 8);

            // (A) per (pixel, corner): compute sample offset + weight
            {
                int dy = k / 3 - 1, dx = k % 3 - 1;
                float offy = offp[((size_t)(b * 72 + s * 18 + 2 * k) * HH + y) * WW + pA];
                float offx = offp[((size_t)(b * 72 + s * 18 + 2 * k + 1) * HH + y) * WW + pA];
                float py  = (float)(y + dy) + offy;
                float px_ = (float)(pA + dx) + offx;
                float y0f = floorf(py), x0f = floorf(px_);
                float wy1 = py - y0f, wx1 = px_ - x0f;
                int yt = (int)y0f + (cA >> 1);
                int xt = (int)x0f + (cA & 1);
                float wt = ((cA >> 1) ? wy1 : 1.f - wy1) * ((cA & 1) ? wx1 : 1.f - wx1);
                bool valid = (yt >= 0) && (yt < HH) && (xt >= 0) && (xt < WW);
                wt = valid ? wt : 0.f;
                int yi = min(max(yt, 0), HH - 1);
                int xi = min(max(xt, 0), WW - 1);
                int2 e = {yi * WW + xi, __builtin_bit_cast(int, wt)};
                *(int2*)&tblI[(pA * 4 + cA) * 2] = e;
            }
            __syncthreads();   // tbl ready; prev MFMA reads of vbuf/wbuf done

            // (B) cooperative gather: wave w owns pixels [w*16, w*16+16)
            float v0[8], v1[8];
            #pragma unroll
            for (int j = 0; j < 8; j++) { v0[j] = 0.f; v1[j] = 0.f; }
            int pg0 = w * 16 + sub;
            int pg1 = w * 16 + 8 + sub;
            #pragma unroll
            for (int c = 0; c < 4; c++) {
                int2 t0 = *(const int2*)&tblI[(pg0 * 4 + c) * 2];
                int2 t1 = *(const int2*)&tblI[(pg1 * 4 + c) * 2];
                const unsigned short* sp0 = hb + (size_t)t0.x * CIN + s * COUT + ch;
                const unsigned short* sp1 = hb + (size_t)t1.x * CIN + s * COUT + ch;
                bf16x8 d0 = *(const bf16x8*)sp0;
                bf16x8 d1 = *(const bf16x8*)sp1;
                float w0 = __builtin_bit_cast(float, t0.y);
                float w1 = __builtin_bit_cast(float, t1.y);
                #pragma unroll
                for (int j = 0; j < 8; j++) {
                    v0[j] = fmaf(w0, bf2f((unsigned short)d0[j]), v0[j]);
                    v1[j] = fmaf(w1, bf2f((unsigned short)d1[j]), v1[j]);
                }
            }
            // pack to bf16 and write vbuf
            {
                u32x4 q0, q1;
                #pragma unroll
                for (int j = 0; j < 4; j++) {
                    q0[j] = (unsigned)f2bf(v0[2 * j]) | ((unsigned)f2bf(v0[2 * j + 1]) << 16);
                    q1[j] = (unsigned)f2bf(v1[2 * j]) | ((unsigned)f2bf(v1[2 * j + 1]) << 16);
                }
                *(u32x4*)&vbufS[pg0 * 72 + ch] = q0;
                *(u32x4*)&vbufS[pg1 * 72 + ch] = q1;
            }
            {
                int wo = tid >> 2, wpart = tid & 3;
                *(bf16x8*)(&wbufS[wo * 72 + wpart * 16])     = wr0;
                *(bf16x8*)(&wbufS[wo * 72 + wpart * 16 + 8]) = wr1;
            }
            __syncthreads();   // vbuf/wbuf ready

            // (C) MFMA: D[px][o] += V[px][cin] * W^T[o][cin]
            #pragma unroll
            for (int ks = 0; ks < 2; ks++) {
                bf16x8 a = *(const bf16x8*)(&vbufS[(w * 16 + lm) * 72 + ks * 32 + lk * 8]);
                #pragma unroll
                for (int nt = 0; nt < 4; nt++) {
                    bf16x8 bb = *(const bf16x8*)(&wbufS[(nt * 16 + lm) * 72 + ks * 32 + lk * 8]);
                    acc[nt] = __builtin_amdgcn_mfma_f32_16x16x32_bf16(a, bb, acc[nt], 0, 0, 0);
                }
            }
        }
    }

    // epilogue: transpose via LDS, coalesced row stores
    #pragma unroll
    for (int nt = 0; nt < 4; nt++) {
        *(f32x4*)(&outT[(nt * 16 + lm) * 68 + w * 16 + lk * 4]) = acc[nt];
    }
    __syncthreads();
    {
        int o = tid >> 2, xp = (tid & 3) * 16;
        float* dst = out + (((size_t)(b * COUT + o)) * HH + y) * WW + xp;
        #pragma unroll
        for (int q = 0; q < 4; q++) {
            *(float4*)(dst + q * 4) = *(const float4*)(&outT[o * 68 + xp + q * 4]);
        }
    }
}

extern "C" void kernel_launch(void* const* d_in, const int* in_sizes, int n_in,
                              void* d_out, int out_size, void* d_ws, size_t ws_size,
                              hipStream_t stream) {
    const float* x        = (const float*)d_in[0];
    const float* bn_gamma = (const float*)d_in[1];
    const float* bn_beta  = (const float*)d_in[2];
    const float* bn_mean  = (const float*)d_in[3];
    const float* bn_var   = (const float*)d_in[4];
    const float* offset_w = (const float*)d_in[5];
    const float* offset_b = (const float*)d_in[6];
    const float* dconv_w  = (const float*)d_in[7];
    const float* dconv_b  = (const float*)d_in[8];
    float* out = (float*)d_out;
    float* ws  = (float*)d_ws;

    unsigned short* hbf = (unsigned short*)(ws + WS_HBF);

    prep_kernel<<<1, 256, 0, stream>>>(bn_gamma, bn_beta, bn_mean, bn_var, dconv_b, ws);
    wtrans_kernel<<<(WOB_ELEMS + 255) / 256, 256, 0, stream>>>(dconv_w, offset_w, ws);
    bn_transpose_kernel<<<dim3(4, 64, 8), 256, 0, stream>>>(x, ws, hbf);
    offconv_kernel<<<dim3(64, 8), 256, 0, stream>>>(hbf, offset_b,
                                                    (const unsigned short*)(ws + WS_WOB),
                                                    ws + WS_OFFS);
    deform_kernel<<<dim3(64, 8), 256, 0, stream>>>(hbf, ws + WS_OFFS,
                                                   (const unsigned short*)(ws + WS_WDT),
                                                   ws + WS_BSUM, out);
}

// Round 6
// 100.297 us; speedup vs baseline: 11.5616x; 1.2644x over previous
//
#include <hip/hip_runtime.h>

#define KK 3
#define CIN 256
#define COUT 64
#define NSPLIT 4
#define BB 8
#define HH 64
#define WW 64
#define K2 9
#define OC 18          // 2*K*K offset channels
#define EPS 1e-5f

typedef __attribute__((ext_vector_type(8))) short bf16x8;
typedef __attribute__((ext_vector_type(4))) float f32x4;
typedef __attribute__((ext_vector_type(4))) unsigned int u32x4;

// ---- workspace layout (in floats) ----
#define WS_SCALE 0
#define WS_BIAS  256
#define WS_BSUM  512
#define WS_HBF   1024
#define HBF_FLOATS (BB*HH*WW*CIN/2)        // bf16 h, NHWC: 4,194,304 floats
#define WS_OFFS  (WS_HBF + HBF_FLOATS)
#define OFFS_SIZE (BB*72*HH*WW)            // 2,359,296
#define WS_WDT   (WS_OFFS + OFFS_SIZE)     // bf16 [s][k][o][cin]: 147,456 shorts
#define WS_WOB   (WS_WDT + NSPLIT*K2*COUT*COUT/2)
#define WOB_ELEMS (K2*80*CIN)              // bf16 [k][sc(80)][cin]: 184,320 shorts

// fp32 -> bf16 RNE
__device__ __host__ inline unsigned short f2bf(float f) {
    unsigned int u = __builtin_bit_cast(unsigned int, f);
    unsigned int r = (u + 0x7fffu + ((u >> 16) & 1u)) >> 16;
    return (unsigned short)r;
}
__device__ inline float bf2f(unsigned short u) {
    return __builtin_bit_cast(float, (unsigned int)u << 16);
}

// K0: per-channel BN scale/bias + summed dconv bias
__global__ void prep_kernel(const float* __restrict__ g, const float* __restrict__ be,
                            const float* __restrict__ mn, const float* __restrict__ vr,
                            const float* __restrict__ db, float* __restrict__ ws) {
    int t = threadIdx.x;
    if (t < CIN) {
        float inv = 1.0f / sqrtf(vr[t] + EPS);
        float sc = g[t] * inv;
        ws[WS_SCALE + t] = sc;
        ws[WS_BIAS + t]  = be[t] - mn[t] * sc;
    }
    if (t < COUT) {
        float s = 0.f;
        for (int i = 0; i < NSPLIT; i++) s += db[i * COUT + t];
        ws[WS_BSUM + t] = s;
    }
}

// K0b: weight transposes (both bf16)
__global__ void wtrans_kernel(const float* __restrict__ dw, const float* __restrict__ ow,
                              float* __restrict__ ws) {
    int tid = blockIdx.x * blockDim.x + threadIdx.x;
    if (tid < NSPLIT * K2 * COUT * COUT) {
        int cin = tid & 63;
        int o = (tid >> 6) & 63;
        int k = (tid / 4096) % 9;
        int s = tid / 36864;
        ((unsigned short*)(ws + WS_WDT))[tid] = f2bf(dw[((s * COUT + o) * COUT + cin) * 9 + k]);
    }
    if (tid < WOB_ELEMS) {
        int cin = tid & 255;
        int sc = (tid >> 8) % 80;
        int k = tid / 20480;
        unsigned short v = 0;
        if (sc < 72) {
            int s = sc / 18, c = sc % 18;
            v = f2bf(ow[((s * OC + c) * CIN + cin) * 9 + k]);
        }
        ((unsigned short*)(ws + WS_WOB))[tid] = v;
    }
}

// K1: BN+ReLU, NCHW -> bf16 NHWC
__global__ __launch_bounds__(256) void bn_transpose_kernel(const float* __restrict__ x,
                                                           const float* __restrict__ scb,
                                                           unsigned short* __restrict__ hbf) {
    __shared__ float tile[64 * 65];
    int cg = blockIdx.x;
    int y  = blockIdx.y;
    int b  = blockIdx.z;
    int lane = threadIdx.x & 63;
    int grp  = threadIdx.x >> 6;
    #pragma unroll
    for (int i = 0; i < 16; i++) {
        int cl = grp * 16 + i;
        int c  = cg * 64 + cl;
        float v = x[((b * CIN + c) * HH + y) * WW + lane];
        float h = fmaxf(fmaf(v, scb[c], scb[256 + c]), 0.f);
        tile[cl * 65 + lane] = h;
    }
    __syncthreads();
    int cpair = threadIdx.x & 31;
    int pxg   = threadIdx.x >> 5;
    #pragma unroll
    for (int i = 0; i < 8; i++) {
        int px = pxg * 8 + i;
        unsigned int u0 = f2bf(tile[(cpair * 2) * 65 + px]);
        unsigned int u1 = f2bf(tile[(cpair * 2 + 1) * 65 + px]);
        *(unsigned int*)&hbf[((size_t)(b * HH + y) * WW + px) * CIN + cg * 64 + cpair * 2] =
            u0 | (u1 << 16);
    }
}

// K2: offset conv via bf16 MFMA. Block = (b,y): M=64 px, N=80, K=256/tap.
__global__ __launch_bounds__(256) void offconv_kernel(const unsigned short* __restrict__ hbf,
                                                      const float* __restrict__ offb,
                                                      const unsigned short* __restrict__ woB,
                                                      float* __restrict__ offs_out) {
    __shared__ unsigned short wlds[80 * 264];
    int tid = threadIdx.x;
    int bid = blockIdx.x + 64 * blockIdx.y;
    int b = bid & 7;
    int y = bid >> 3;
    int w  = tid >> 6;
    int l  = tid & 63;
    int lm = l & 15, lk = l >> 4;
    int px = w * 16 + lm;

    f32x4 acc[5];
    #pragma unroll
    for (int nt = 0; nt < 5; nt++) {
        int sc = nt * 16 + lm;
        float ob = (sc < 72) ? offb[sc] : 0.f;
        acc[nt] = (f32x4){ob, ob, ob, ob};
    }
    const unsigned short* hb = hbf + (size_t)b * HH * WW * CIN;
    const bf16x8 zero = {};

    for (int k = 0; k < 9; k++) {
        int dy = k / 3 - 1, dx = k % 3 - 1;
        int ry = y + dy;
        if ((unsigned)ry >= (unsigned)HH) continue;
        __syncthreads();
        const unsigned short* src = woB + (size_t)k * 80 * 256;
        #pragma unroll
        for (int t = 0; t < 10; t++) {
            int idx = tid + t * 256;
            int sc = idx >> 5;
            int co = (idx & 31) * 8;
            *(bf16x8*)&wlds[sc * 264 + co] = *(const bf16x8*)&src[sc * 256 + co];
        }
        __syncthreads();

        int rx = px + dx;
        bool vx = (unsigned)rx < (unsigned)WW;
        const unsigned short* arow = hb + ((size_t)ry * WW + rx) * CIN + lk * 8;
        #pragma unroll
        for (int kt = 0; kt < 8; kt++) {
            bf16x8 a = vx ? *(const bf16x8*)(arow + kt * 32) : zero;
            #pragma unroll
            for (int nt = 0; nt < 5; nt++) {
                bf16x8 bb = *(const bf16x8*)&wlds[(nt * 16 + lm) * 264 + kt * 32 + lk * 8];
                acc[nt] = __builtin_amdgcn_mfma_f32_16x16x32_bf16(a, bb, acc[nt], 0, 0, 0);
            }
        }
    }

    #pragma unroll
    for (int nt = 0; nt < 5; nt++) {
        int sc = nt * 16 + lm;
        if (sc < 72) {
            float4 v = {acc[nt][0], acc[nt][1], acc[nt][2], acc[nt][3]};
            *(float4*)&offs_out[((size_t)(b * 72 + sc) * HH + y) * WW + w * 16 + lk * 4] = v;
        }
    }
}

// K3: deformable conv via bf16 MFMA. 512 threads = 2 halves x 4 waves.
// Half h handles splits {2h, 2h+1} (18 iters); halves combine via LDS at the end.
__global__ __launch_bounds__(512) void deform_kernel(const unsigned short* __restrict__ hbf,
                                                     const float* __restrict__ offp,
                                                     const unsigned short* __restrict__ wdT,
                                                     const float* __restrict__ bsum,
                                                     float* __restrict__ out) {
    // per-half region: vbuf(9216B) | wbuf(9216B) | tbl(2048B) = 20480B; reused as outT (17408B)
    __shared__ __align__(16) char lds[2][20480];

    int tid = threadIdx.x;
    int bid = blockIdx.x + 64 * blockIdx.y;   // XCD swizzle: b = bid & 7
    int b = bid & 7;
    int y = bid >> 3;

    int h  = tid >> 8;        // half (0,1)
    int t8 = tid & 255;       // index within half
    int l  = tid & 63;
    int w4 = t8 >> 6;         // wave within half (0..3)
    int lm = l & 15;
    int lk = l >> 4;
    int pA = t8 >> 2;         // table pixel (0..63)
    int cA = t8 & 3;          // table corner
    int sub = l >> 3;         // gather: pixel-within-group-of-8
    int ch  = (l & 7) * 8;    // gather: channel slice base

    unsigned short* vbufS = (unsigned short*)&lds[h][0];      // [px][72]
    unsigned short* wbufS = (unsigned short*)&lds[h][9216];   // [o][72]
    int*            tblI  = (int*)&lds[h][18432];             // [px][4] {off, wt}

    f32x4 acc[4];
    #pragma unroll
    for (int nt = 0; nt < 4; nt++) {
        float bs = h ? 0.f : bsum[nt * 16 + lm];
        acc[nt] = (f32x4){bs, bs, bs, bs};
    }

    const unsigned short* hb = hbf + (size_t)b * HH * WW * CIN;
    const float* offbase = offp + ((size_t)(b * 72 + 2 * h * 18) * HH + y) * WW + pA;

    // one-ahead offset prefetch (it=0 -> s=2h, k=0)
    float offy_c = offbase[0];
    float offx_c = offbase[HH * WW];

    for (int it = 0; it < 2 * K2; ++it) {
        int sl = it >= K2;             // split-local (0,1)
        int s  = 2 * h + sl;
        int k  = it - sl * K2;

        // (0) issue next iteration's offset loads
        float offy_n = 0.f, offx_n = 0.f;
        if (it + 1 < 2 * K2) {
            int sl2 = (it + 1) >= K2;
            int k2  = (it + 1) - sl2 * K2;
            const float* oa = offbase + (size_t)(sl2 * 18 + 2 * k2) * (HH * WW);
            offy_n = oa[0];
            offx_n = oa[HH * WW];
        }

        // (0b) issue weight loads early (32B/thread, contiguous)
        const unsigned short* wsrc = wdT + (size_t)((s * 9 + k) * 64) * 64;
        bf16x8 wr0 = *(const bf16x8*)(wsrc + t8 * 16);
        bf16x8 wr1 = *(const bf16x8*)(wsrc + t8 * 16 + 8);

        // (A) per (pixel, corner): sample offset + weight -> tbl
        {
            int dy = k / 3 - 1, dx = k % 3 - 1;
            float py  = (float)(y + dy) + offy_c;
            float px_ = (float)(pA + dx) + offx_c;
            float y0f = floorf(py), x0f = floorf(px_);
            float wy1 = py - y0f, wx1 = px_ - x0f;
            int yt = (int)y0f + (cA >> 1);
            int xt = (int)x0f + (cA & 1);
            float wt = ((cA >> 1) ? wy1 : 1.f - wy1) * ((cA & 1) ? wx1 : 1.f - wx1);
            bool valid = (yt >= 0) && (yt < HH) && (xt >= 0) && (xt < WW);
            wt = valid ? wt : 0.f;
            int yi = min(max(yt, 0), HH - 1);
            int xi = min(max(xt, 0), WW - 1);
            int2 e = {yi * WW + xi, __builtin_bit_cast(int, wt)};
            *(int2*)&tblI[(pA * 4 + cA) * 2] = e;
        }
        __syncthreads();   // tbl ready; prev MFMA reads of vbuf/wbuf done

        // (B) cooperative gather: wave w4 owns pixels [w4*16, w4*16+16)
        float v0[8], v1[8];
        #pragma unroll
        for (int j = 0; j < 8; j++) { v0[j] = 0.f; v1[j] = 0.f; }
        int pg0 = w4 * 16 + sub;
        int pg1 = w4 * 16 + 8 + sub;
        #pragma unroll
        for (int c = 0; c < 4; c++) {
            int2 t0 = *(const int2*)&tblI[(pg0 * 4 + c) * 2];
            int2 t1 = *(const int2*)&tblI[(pg1 * 4 + c) * 2];
            const unsigned short* sp0 = hb + (size_t)t0.x * CIN + s * COUT + ch;
            const unsigned short* sp1 = hb + (size_t)t1.x * CIN + s * COUT + ch;
            bf16x8 d0 = *(const bf16x8*)sp0;
            bf16x8 d1 = *(const bf16x8*)sp1;
            float w0 = __builtin_bit_cast(float, t0.y);
            float w1 = __builtin_bit_cast(float, t1.y);
            #pragma unroll
            for (int j = 0; j < 8; j++) {
                v0[j] = fmaf(w0, bf2f((unsigned short)d0[j]), v0[j]);
                v1[j] = fmaf(w1, bf2f((unsigned short)d1[j]), v1[j]);
            }
        }
        {
            u32x4 q0, q1;
            #pragma unroll
            for (int j = 0; j < 4; j++) {
                q0[j] = (unsigned)f2bf(v0[2 * j]) | ((unsigned)f2bf(v0[2 * j + 1]) << 16);
                q1[j] = (unsigned)f2bf(v1[2 * j]) | ((unsigned)f2bf(v1[2 * j + 1]) << 16);
            }
            *(u32x4*)&vbufS[pg0 * 72 + ch] = q0;
            *(u32x4*)&vbufS[pg1 * 72 + ch] = q1;
        }
        {
            int wo = t8 >> 2, wpart = t8 & 3;
            *(bf16x8*)(&wbufS[wo * 72 + wpart * 16])     = wr0;
            *(bf16x8*)(&wbufS[wo * 72 + wpart * 16 + 8]) = wr1;
        }
        __syncthreads();   // vbuf/wbuf ready

        // (C) MFMA: D[px][o] += V[px][cin] * W^T[o][cin]
        #pragma unroll
        for (int ks = 0; ks < 2; ks++) {
            bf16x8 a = *(const bf16x8*)(&vbufS[(w4 * 16 + lm) * 72 + ks * 32 + lk * 8]);
            #pragma unroll
            for (int nt = 0; nt < 4; nt++) {
                bf16x8 bb = *(const bf16x8*)(&wbufS[(nt * 16 + lm) * 72 + ks * 32 + lk * 8]);
                acc[nt] = __builtin_amdgcn_mfma_f32_16x16x32_bf16(a, bb, acc[nt], 0, 0, 0);
            }
        }

        offy_c = offy_n;
        offx_c = offx_n;
    }

    // epilogue: each half transposes acc into its own region (aliases vbuf/wbuf/tbl),
    // then all 512 threads combine the two halves and store coalesced.
    __syncthreads();   // all MFMA LDS reads complete before alias reuse
    float* outT = (float*)&lds[h][0];   // [o][68]
    #pragma unroll
    for (int nt = 0; nt < 4; nt++) {
        *(f32x4*)(&outT[(nt * 16 + lm) * 68 + w4 * 16 + lk * 4]) = acc[nt];
    }
    __syncthreads();
    {
        const float* o0 = (const float*)&lds[0][0];
        const float* o1 = (const float*)&lds[1][0];
        int o = tid >> 3, xp = (tid & 7) * 8;
        float* dst = out + (((size_t)(b * COUT + o)) * HH + y) * WW + xp;
        #pragma unroll
        for (int q = 0; q < 2; q++) {
            float4 a = *(const float4*)(&o0[o * 68 + xp + q * 4]);
            float4 c = *(const float4*)(&o1[o * 68 + xp + q * 4]);
            float4 r = {a.x + c.x, a.y + c.y, a.z + c.z, a.w + c.w};
            *(float4*)(dst + q * 4) = r;
        }
    }
}

extern "C" void kernel_launch(void* const* d_in, const int* in_sizes, int n_in,
                              void* d_out, int out_size, void* d_ws, size_t ws_size,
                              hipStream_t stream) {
    const float* x        = (const float*)d_in[0];
    const float* bn_gamma = (const float*)d_in[1];
    const float* bn_beta  = (const float*)d_in[2];
    const float* bn_mean  = (const float*)d_in[3];
    const float* bn_var   = (const float*)d_in[4];
    const float* offset_w = (const float*)d_in[5];
    const float* offset_b = (const float*)d_in[6];
    const float* dconv_w  = (const float*)d_in[7];
    const float* dconv_b  = (const float*)d_in[8];
    float* out = (float*)d_out;
    float* ws  = (float*)d_ws;

    unsigned short* hbf = (unsigned short*)(ws + WS_HBF);

    prep_kernel<<<1, 256, 0, stream>>>(bn_gamma, bn_beta, bn_mean, bn_var, dconv_b, ws);
    wtrans_kernel<<<(WOB_ELEMS + 255) / 256, 256, 0, stream>>>(dconv_w, offset_w, ws);
    bn_transpose_kernel<<<dim3(4, 64, 8), 256, 0, stream>>>(x, ws, hbf);
    offconv_kernel<<<dim3(64, 8), 256, 0, stream>>>(hbf, offset_b,
                                                    (const unsigned short*)(ws + WS_WOB),
                                                    ws + WS_OFFS);
    deform_kernel<<<dim3(64, 8), 512, 0, stream>>>(hbf, ws + WS_OFFS,
                                                   (const unsigned short*)(ws + WS_WDT),
                                                   ws + WS_BSUM, out);
}